// Round 4
// baseline (263.089 us; speedup 1.0000x reference)
//
#include <hip/hip_runtime.h>
#include <hip/hip_bf16.h>

#define Bn   4096
#define Sn   128
#define En   768
#define HIDn 384
#define NHn  9
#define NEn  5
#define NECOL 1920        // NE*HID expert columns
#define MAXTILES 41       // max padded m-tiles: floor(4096/128)+9

typedef __attribute__((ext_vector_type(8))) short short8;
typedef __attribute__((ext_vector_type(4))) float f32x4;

__device__ __forceinline__ unsigned short f2bf(float v) {
  unsigned int x = __float_as_uint(v);
  x += 0x7fffu + ((x >> 16) & 1u);   // RNE
  return (unsigned short)(x >> 16);
}
__device__ __forceinline__ float dot4(float4 a, float4 b) {
  return fmaf(a.x, b.x, fmaf(a.y, b.y, fmaf(a.z, b.z, a.w * b.w)));
}
__device__ __forceinline__ void fma4(float4& p, float w, float4 v) {
  p.x = fmaf(w, v.x, p.x); p.y = fmaf(w, v.y, p.y);
  p.z = fmaf(w, v.z, p.z); p.w = fmaf(w, v.w, p.w);
}

// ------------- K1: pack weights to MFMA B-frag layout + counting sort ------
// frag tile = 16 cols x 32 k, entry [lane*8+e] = W[kt*32+(lane>>4)*8+e][nt*16+(lane&15)]
__global__ __launch_bounds__(256) void packsort_kernel(
    const float* __restrict__ ew, const float* __restrict__ g1,
    const int* __restrict__ category,
    unsigned short* __restrict__ Bpe, unsigned short* __restrict__ Bpg,
    int* __restrict__ rowsamp, int* __restrict__ posof, int* __restrict__ meta) {
  const int t = threadIdx.x, lane = t & 63;
  if (blockIdx.x < 2016) {                 // ---- pack ----
    const int pair = blockIdx.x * 4 + (t >> 6);
    const int q = lane >> 4, j = lane & 15;
    const float* src; unsigned short* dst; int kt;
    if (pair < 2880) {                     // expert: 120 ntiles x 24 kt
      int nt = pair / 24; kt = pair % 24;
      int col = nt * 16 + j;
      src = ew + (size_t)(col / HIDn) * (En * HIDn) + (col % HIDn);
      dst = Bpe + (size_t)pair * 512;
    } else {                               // gate: 9 heads x 24 ntiles x 24 kt
      int g = pair - 2880;
      int h = g / 576, rem = g % 576;
      int nt = rem / 24; kt = rem % 24;
      int col = nt * 16 + j;
      src = g1 + (size_t)h * (En * HIDn) + col;
      dst = Bpg + ((size_t)(h * 24 + nt) * 24 + kt) * 512;
    }
    unsigned short outv[8] __attribute__((aligned(16)));
    #pragma unroll
    for (int e = 0; e < 8; ++e) {
      int k = kt * 32 + q * 8 + e;
      outv[e] = f2bf(src[(size_t)k * HIDn]);
    }
    *(uint4*)&dst[lane * 8] = *(const uint4*)outv;
    return;
  }
  // ---- sort (block 2016): stable counting sort by category, 128-padded ----
  __shared__ int hist[NHn][256];
  __shared__ int padbase[NHn], total[NHn];
  __shared__ int tilecat_s[MAXTILES];
  __shared__ int padTiles_s;
  #pragma unroll
  for (int jj = 0; jj < NHn; ++jj) hist[jj][t] = 0;
  __syncthreads();
  for (int i = 0; i < 16; ++i) { int c = category[t * 16 + i]; hist[c][t]++; }
  __syncthreads();
  if (t < NHn) {
    int run = 0;
    for (int x = 0; x < 256; ++x) { int v = hist[t][x]; hist[t][x] = run; run += v; }
    total[t] = run;
  }
  __syncthreads();
  if (t == 0) {
    int pb = 0, mt = 0;
    for (int jj = 0; jj < NHn; ++jj) {
      padbase[jj] = pb;
      int tot = total[jj];
      int nt = (tot + 127) >> 7;
      for (int k2 = 0; k2 < nt; ++k2) {
        meta[1 + mt + k2] = jj;
        int vv = tot - (k2 << 7); if (vv > 128) vv = 128;
        meta[64 + mt + k2] = vv;
        tilecat_s[mt + k2] = jj;
      }
      mt += nt; pb += nt << 7;
    }
    meta[0] = mt; padTiles_s = mt;
  }
  __syncthreads();
  const int padM = padTiles_s << 7;
  for (int mm = t; mm < padM; mm += 256) {        // default-fill padding rows
    int h = tilecat_s[mm >> 7];
    if (mm - padbase[h] >= total[h]) rowsamp[mm] = 0;
  }
  for (int i = 0; i < 16; ++i) {                  // stable scatter
    int idx = t * 16 + i; int c = category[idx];
    int off = hist[c][t]++;
    int pp = padbase[c] + off;
    rowsamp[pp] = idx;
    posof[idx] = pp;
  }
}

// ---------------- K2: fused mask+softmax+pool -> A-fragments ----------------
// 1 block/sample, 4 waves, block-wide balanced row list. Writes pooled sample
// directly in MFMA A-fragment layout, twice: natural order (Ape, for gemme)
// and category-sorted order (Apg, for gemmg). Seeds glog with gate_b2[cat].
__global__ __launch_bounds__(256) void pool_kernel(
    const float* __restrict__ feature, const int* __restrict__ masks,
    const float* __restrict__ attn_w, const int* __restrict__ category,
    const float* __restrict__ gb2, const int* __restrict__ posof,
    unsigned short* __restrict__ Ape, unsigned short* __restrict__ Apg,
    float* __restrict__ glog) {
  __shared__ __align__(16) float pbuf[4][768];
  __shared__ float sbuf[4];
  __shared__ int rowlist[128];
  __shared__ int rcount;
  const int t = threadIdx.x, lane = t & 63, wid = t >> 6;
  const int b = blockIdx.x;
  if (t == 0) rcount = 0;
  const float4* aw = (const float4*)attn_w;
  const float4 aw0 = aw[lane], aw1 = aw[64 + lane], aw2 = aw[128 + lane];
  const float4* fb = (const float4*)(feature + (size_t)b * (Sn * En));
  __syncthreads();
  unsigned long long bal = __ballot(lane < 32 && masks[b * Sn + wid * 32 + (lane & 31)] != 0);
  unsigned int m = (unsigned int)bal;
  int cnt = __popc(m);
  int base = 0;
  if (lane == 0) base = atomicAdd(&rcount, cnt);
  base = __shfl(base, 0);
  if (lane < 32 && ((m >> lane) & 1u))
    rowlist[base + __popc(m & ((1u << lane) - 1u))] = wid * 32 + lane;
  __syncthreads();
  const int nr = rcount;
  int idxreg = 0;
  if (lane < 32 && (wid + 4 * lane) < 128) idxreg = rowlist[wid + 4 * lane];
  const int niter = (nr > wid) ? ((nr - wid + 3) >> 2) : 0;
  float4 p0 = {0,0,0,0}, p1 = {0,0,0,0}, p2 = {0,0,0,0};
  float lsum = 0.f;
  if (niter) {
    int row = __shfl(idxreg, 0);
    const float4* rp = fb + row * (En / 4);
    float4 c0 = rp[lane], c1 = rp[64 + lane], c2 = rp[128 + lane];
    for (int j = 1; j < niter; ++j) {
      int row2 = __shfl(idxreg, j);
      const float4* rp2 = fb + row2 * (En / 4);
      float4 n0 = rp2[lane], n1 = rp2[64 + lane], n2 = rp2[128 + lane];
      float part = dot4(c0, aw0) + dot4(c1, aw1) + dot4(c2, aw2);
      #pragma unroll
      for (int off = 32; off; off >>= 1) part += __shfl_xor(part, off);
      float w = __expf(part);              // |score| small -> no max-sub needed
      lsum += w;
      fma4(p0, w, c0); fma4(p1, w, c1); fma4(p2, w, c2);
      c0 = n0; c1 = n1; c2 = n2;
    }
    float part = dot4(c0, aw0) + dot4(c1, aw1) + dot4(c2, aw2);
    #pragma unroll
    for (int off = 32; off; off >>= 1) part += __shfl_xor(part, off);
    float w = __expf(part);
    lsum += w;
    fma4(p0, w, c0); fma4(p1, w, c1); fma4(p2, w, c2);
  }
  ((float4*)pbuf[wid])[lane] = p0;
  ((float4*)pbuf[wid])[64 + lane] = p1;
  ((float4*)pbuf[wid])[128 + lane] = p2;
  if (lane == 0) sbuf[wid] = lsum;
  __syncthreads();
  float total = sbuf[0] + sbuf[1] + sbuf[2] + sbuf[3];
  if (total == 0.f) {                      // all rows masked: uniform alpha
    p0 = p1 = p2 = float4{0,0,0,0};
    for (int s = 0; s < 32; ++s) {
      const float4* rp = fb + (wid * 32 + s) * (En / 4);
      fma4(p0, 1.f, rp[lane]); fma4(p1, 1.f, rp[64 + lane]); fma4(p2, 1.f, rp[128 + lane]);
    }
    ((float4*)pbuf[wid])[lane] = p0;
    ((float4*)pbuf[wid])[64 + lane] = p1;
    ((float4*)pbuf[wid])[128 + lane] = p2;
    __syncthreads();
    total = 128.f;
  }
  const float inv = 1.f / total;
  if (t < 192) {                            // elems k = 4t..4t+3
    float4 s0 = ((const float4*)pbuf[0])[t];
    float4 s1 = ((const float4*)pbuf[1])[t];
    float4 s2 = ((const float4*)pbuf[2])[t];
    float4 s3 = ((const float4*)pbuf[3])[t];
    ushort4 u;
    u.x = f2bf((s0.x+s1.x+s2.x+s3.x) * inv);
    u.y = f2bf((s0.y+s1.y+s2.y+s3.y) * inv);
    u.z = f2bf((s0.z+s1.z+s2.z+s3.z) * inv);
    u.w = f2bf((s0.w+s1.w+s2.w+s3.w) * inv);
    const int kt = t >> 3, q = (t >> 1) & 3, e = (t & 1) * 4;
    *(ushort4*)&Ape[((size_t)(b >> 4) * 24 + kt) * 512 + ((b & 15) + (q << 4)) * 8 + e] = u;
    const int pp = posof[b];
    *(ushort4*)&Apg[((size_t)(pp >> 4) * 24 + kt) * 512 + ((pp & 15) + (q << 4)) * 8 + e] = u;
  }
  if (t < 5) glog[(size_t)b * 5 + t] = gb2[category[b] * 5 + t];
}

// ------- K3: gate GEMM, LDS-free frag loads: glog += relu(A@W1+b1)@W2 ------
__global__ __launch_bounds__(256) void gemmg_kernel(
    const unsigned short* __restrict__ Apg, const unsigned short* __restrict__ Bpg,
    const float* __restrict__ gb1, const float* __restrict__ g2,
    const int* __restrict__ rowsamp, const int* __restrict__ meta,
    float* __restrict__ glog) {
  const int mt = blockIdx.y;
  if (mt >= meta[0]) return;
  const int h = meta[1 + mt];
  const int valid = meta[64 + mt];
  __shared__ float w2lds[640];
  __shared__ int rs[128];
  const int t = threadIdx.x, lane = t & 63, wid = t >> 6;
  const int wm = wid >> 1, wn = wid & 1;
  const int bx = blockIdx.x;
  if (t < 128) rs[t] = rowsamp[mt * 128 + t];
  const float* w2src = g2 + ((size_t)h * HIDn + bx * 128) * 5;
  for (int idx = t; idx < 640; idx += 256) w2lds[idx] = w2src[idx];
  const int amt0 = mt * 8 + wm * 4;
  const int nt0 = bx * 8 + wn * 4;
  f32x4 acc[4][4] = {};
  #pragma unroll 2
  for (int kt = 0; kt < 24; ++kt) {
    short8 af[4], bfv[4];
    #pragma unroll
    for (int i = 0; i < 4; ++i)
      af[i] = *(const short8*)&Apg[((size_t)(amt0 + i) * 24 + kt) * 512 + lane * 8];
    #pragma unroll
    for (int jj = 0; jj < 4; ++jj)
      bfv[jj] = *(const short8*)&Bpg[(((size_t)h * 24 + nt0 + jj) * 24 + kt) * 512 + lane * 8];
    #pragma unroll
    for (int i = 0; i < 4; ++i)
      #pragma unroll
      for (int jj = 0; jj < 4; ++jj)
        acc[i][jj] = __builtin_amdgcn_mfma_f32_16x16x32_bf16(af[i], bfv[jj], acc[i][jj], 0, 0, 0);
  }
  __syncthreads();                          // w2lds + rs ready
  const int lrb = wm * 64 + ((lane >> 4) << 2);
  const int cb = wn * 64 + (lane & 15);
  #pragma unroll
  for (int i = 0; i < 4; ++i) {
    #pragma unroll
    for (int rr = 0; rr < 4; ++rr) {
      const int lrow = lrb + i * 16 + rr;
      float s[5] = {0.f, 0.f, 0.f, 0.f, 0.f};
      #pragma unroll
      for (int jj = 0; jj < 4; ++jj) {
        int cl = cb + jj * 16;
        float v = acc[i][jj][rr] + gb1[h * HIDn + bx * 128 + cl];
        v = fmaxf(v, 0.f);
        #pragma unroll
        for (int k = 0; k < 5; ++k) s[k] = fmaf(v, w2lds[cl * 5 + k], s[k]);
      }
      #pragma unroll
      for (int k = 0; k < 5; ++k)
        #pragma unroll
        for (int off = 8; off; off >>= 1) s[k] += __shfl_xor(s[k], off);
      if ((lane & 15) == 0 && lrow < valid) {
        int samp = rs[lrow];
        #pragma unroll
        for (int k = 0; k < 5; ++k) atomicAdd(&glog[(size_t)samp * 5 + k], s[k]);
      }
    }
  }
}

// ------- K4: expert GEMM, LDS-free; epilogue: per-expert head partials -----
// Each 128-col block lies in exactly one expert (384 = 3*128). No glog dep.
__global__ __launch_bounds__(256) void gemme_kernel(
    const unsigned short* __restrict__ Ape, const unsigned short* __restrict__ Bpe,
    const float* __restrict__ eb, const int* __restrict__ category,
    const float* __restrict__ hw, float* __restrict__ partial) {
  __shared__ float hwlds[NHn * HIDn];
  __shared__ float plds[2][128];
  const int t = threadIdx.x, lane = t & 63, wid = t >> 6;
  const int wm = wid >> 1, wn = wid & 1;
  const int m0 = blockIdx.y * 128;
  const int bx = blockIdx.x;
  for (int idx = t; idx < NHn * HIDn; idx += 256) hwlds[idx] = hw[idx];
  const int amt0 = blockIdx.y * 8 + wm * 4;
  const int nt0 = bx * 8 + wn * 4;
  f32x4 acc[4][4] = {};
  #pragma unroll 2
  for (int kt = 0; kt < 24; ++kt) {
    short8 af[4], bfv[4];
    #pragma unroll
    for (int i = 0; i < 4; ++i)
      af[i] = *(const short8*)&Ape[((size_t)(amt0 + i) * 24 + kt) * 512 + lane * 8];
    #pragma unroll
    for (int jj = 0; jj < 4; ++jj)
      bfv[jj] = *(const short8*)&Bpe[((size_t)(nt0 + jj) * 24 + kt) * 512 + lane * 8];
    #pragma unroll
    for (int i = 0; i < 4; ++i)
      #pragma unroll
      for (int jj = 0; jj < 4; ++jj)
        acc[i][jj] = __builtin_amdgcn_mfma_f32_16x16x32_bf16(af[i], bfv[jj], acc[i][jj], 0, 0, 0);
  }
  __syncthreads();                          // hwlds ready
  const int kexp = bx / 3;
  const int lcolbase = (bx % 3) * 128;
  const int lrb = wm * 64 + ((lane >> 4) << 2);
  const int cb = wn * 64 + (lane & 15);
  float sums[4][4];
  #pragma unroll
  for (int i = 0; i < 4; ++i) {
    #pragma unroll
    for (int rr = 0; rr < 4; ++rr) {
      const int row = m0 + lrb + i * 16 + rr;
      const int cat = category[row];
      float s = 0.f;
      #pragma unroll
      for (int jj = 0; jj < 4; ++jj) {
        int cl = cb + jj * 16;
        float v = acc[i][jj][rr] + eb[bx * 128 + cl];
        v = fmaxf(v, 0.f);
        s = fmaf(v, hwlds[cat * HIDn + lcolbase + cl], s);
      }
      #pragma unroll
      for (int off = 8; off; off >>= 1) s += __shfl_xor(s, off);
      sums[i][rr] = s;
    }
  }
  if ((lane & 15) == 0) {
    #pragma unroll
    for (int i = 0; i < 4; ++i)
      #pragma unroll
      for (int rr = 0; rr < 4; ++rr)
        plds[wn][lrb + i * 16 + rr] = sums[i][rr];
  }
  __syncthreads();
  if (t < 128) partial[(size_t)bx * Bn + m0 + t] = plds[0][t] + plds[1][t];
}

// ------------- K5: gate softmax + expert combine + head bias + sigmoid -----
__global__ __launch_bounds__(256) void final_kernel(
    const float* __restrict__ partial, const float* __restrict__ glog,
    const int* __restrict__ category, const float* __restrict__ hb,
    float* __restrict__ out) {
  const int row = blockIdx.x * 256 + threadIdx.x;
  const float* gl = glog + (size_t)row * 5;
  float g0 = gl[0], g1 = gl[1], g2v = gl[2], g3 = gl[3], g4 = gl[4];
  float mx = fmaxf(fmaxf(fmaxf(g0, g1), fmaxf(g2v, g3)), g4);
  float e0 = __expf(g0 - mx), e1 = __expf(g1 - mx), e2 = __expf(g2v - mx),
        e3 = __expf(g3 - mx), e4 = __expf(g4 - mx);
  float einv = 1.f / (e0 + e1 + e2 + e3 + e4);
  float gk[5] = {e0, e1, e2, e3, e4};
  float s = 0.f;
  #pragma unroll
  for (int k = 0; k < 5; ++k) {
    float ps = partial[(size_t)(3 * k) * Bn + row]
             + partial[(size_t)(3 * k + 1) * Bn + row]
             + partial[(size_t)(3 * k + 2) * Bn + row];
    s = fmaf(gk[k] * einv, ps, s);
  }
  s += hb[category[row]];
  out[row] = 1.f / (1.f + __expf(-s));
}

extern "C" void kernel_launch(void* const* d_in, const int* in_sizes, int n_in,
                              void* d_out, int out_size, void* d_ws, size_t ws_size,
                              hipStream_t stream) {
  const float* feature  = (const float*)d_in[0];
  const int*   masks    = (const int*)d_in[1];
  const int*   category = (const int*)d_in[2];
  const float* attn_w   = (const float*)d_in[3];
  // d_in[4] attn_b cancels in softmax
  const float* gate_w1  = (const float*)d_in[5];
  const float* gate_b1  = (const float*)d_in[6];
  const float* gate_w2  = (const float*)d_in[7];
  const float* gate_b2  = (const float*)d_in[8];
  const float* expert_w = (const float*)d_in[9];
  const float* expert_b = (const float*)d_in[10];
  const float* head_w   = (const float*)d_in[11];
  const float* head_b   = (const float*)d_in[12];
  float* out = (float*)d_out;

  char* ws = (char*)d_ws;
  unsigned short* Ape = (unsigned short*)(ws);                //  6,291,456 B
  unsigned short* Apg = (unsigned short*)(ws + 6291456);      //  8,060,928 B
  unsigned short* Bpe = (unsigned short*)(ws + 14352384);     //  2,949,120 B
  unsigned short* Bpg = (unsigned short*)(ws + 17301504);     //  5,308,416 B
  int* rowsamp        = (int*)(ws + 22609920);                //     20,992 B
  int* posof          = (int*)(ws + 22630912);                //     16,384 B
  int* meta           = (int*)(ws + 22647296);                //        512 B
  float* glog         = (float*)(ws + 22647808);              //     81,920 B
  float* partial      = (float*)(ws + 22729728);              //    245,760 B

  packsort_kernel<<<dim3(2017), dim3(256), 0, stream>>>(expert_w, gate_w1, category,
                                                        Bpe, Bpg, rowsamp, posof, meta);
  pool_kernel<<<dim3(4096), dim3(256), 0, stream>>>(feature, masks, attn_w, category,
                                                    gate_b2, posof, Ape, Apg, glog);
  gemmg_kernel<<<dim3(3, MAXTILES), dim3(256), 0, stream>>>(Apg, Bpg, gate_b1, gate_w2,
                                                            rowsamp, meta, glog);
  gemme_kernel<<<dim3(15, 32), dim3(256), 0, stream>>>(Ape, Bpe, expert_b,
                                                       category, head_w, partial);
  final_kernel<<<dim3(16), dim3(256), 0, stream>>>(partial, glog, category, head_b, out);
}

// Round 5
// 218.402 us; speedup vs baseline: 1.2046x; 1.2046x over previous
//
#include <hip/hip_runtime.h>
#include <hip/hip_bf16.h>

#define Bn   4096
#define Sn   128
#define En   768
#define HIDn 384
#define NHn  9
#define NEn  5
#define MAXTILES 41       // max padded m-tiles: 32 + up to 8 from per-cat rounding

typedef __attribute__((ext_vector_type(8))) short short8;
typedef __attribute__((ext_vector_type(4))) float f32x4;

__device__ __forceinline__ unsigned short f2bf(float v) {
  unsigned int x = __float_as_uint(v);
  x += 0x7fffu + ((x >> 16) & 1u);   // RNE
  return (unsigned short)(x >> 16);
}
__device__ __forceinline__ float dot4(float4 a, float4 b) {
  return fmaf(a.x, b.x, fmaf(a.y, b.y, fmaf(a.z, b.z, a.w * b.w)));
}
__device__ __forceinline__ void fma4(float4& p, float w, float4 v) {
  p.x = fmaf(w, v.x, p.x); p.y = fmaf(w, v.y, p.y);
  p.z = fmaf(w, v.z, p.z); p.w = fmaf(w, v.w, p.w);
}

// ====== K1: pool (blocks 0..4095) | pack (4096..6111) | sort (6112) =========
__global__ __launch_bounds__(256) void prep_kernel(
    const float* __restrict__ feature, const int* __restrict__ masks,
    const float* __restrict__ attn_w, const float* __restrict__ ew,
    const float* __restrict__ g1, const int* __restrict__ category,
    unsigned short* __restrict__ pooled, unsigned short* __restrict__ Bpe,
    unsigned short* __restrict__ Bpg, int* __restrict__ rowsamp,
    int* __restrict__ meta) {
  __shared__ __align__(16) union {
    struct { float pbuf[4][768]; float sbuf[4]; } pool;
    struct { int hist[NHn][256]; int padbase[NHn]; int total[NHn];
             int tilecat[MAXTILES]; int padTiles; } srt;
  } sm;
  const int t = threadIdx.x, lane = t & 63, wid = t >> 6;
  const int bid = blockIdx.x;

  if (bid < Bn) {                          // ---------------- pool ----------
    const int b = bid;
    const float4* aw = (const float4*)attn_w;
    const float4 aw0 = aw[lane], aw1 = aw[64 + lane], aw2 = aw[128 + lane];
    const float4* fb = (const float4*)(feature + (size_t)b * (Sn * En));
    unsigned long long bal = __ballot(lane < 32 && masks[b * Sn + wid * 32 + (lane & 31)] != 0);
    unsigned int m = (unsigned int)bal;
    float4 p0 = {0,0,0,0}, p1 = {0,0,0,0}, p2 = {0,0,0,0};
    float lsum = 0.f;
    if (m) {
      int s = __builtin_ctz(m); m &= m - 1;
      const float4* rp = fb + (wid * 32 + s) * (En / 4);
      float4 c0 = rp[lane], c1 = rp[64 + lane], c2 = rp[128 + lane];
      while (m) {
        int s2 = __builtin_ctz(m); m &= m - 1;
        const float4* rp2 = fb + (wid * 32 + s2) * (En / 4);
        float4 n0 = rp2[lane], n1 = rp2[64 + lane], n2 = rp2[128 + lane];
        float part = dot4(c0, aw0) + dot4(c1, aw1) + dot4(c2, aw2);
        #pragma unroll
        for (int off = 32; off; off >>= 1) part += __shfl_xor(part, off);
        float w = __expf(part);            // |score| small -> no max-sub needed
        lsum += w;
        fma4(p0, w, c0); fma4(p1, w, c1); fma4(p2, w, c2);
        c0 = n0; c1 = n1; c2 = n2;
      }
      float part = dot4(c0, aw0) + dot4(c1, aw1) + dot4(c2, aw2);
      #pragma unroll
      for (int off = 32; off; off >>= 1) part += __shfl_xor(part, off);
      float w = __expf(part);
      lsum += w;
      fma4(p0, w, c0); fma4(p1, w, c1); fma4(p2, w, c2);
    }
    ((float4*)sm.pool.pbuf[wid])[lane] = p0;
    ((float4*)sm.pool.pbuf[wid])[64 + lane] = p1;
    ((float4*)sm.pool.pbuf[wid])[128 + lane] = p2;
    if (lane == 0) sm.pool.sbuf[wid] = lsum;
    __syncthreads();
    float total = sm.pool.sbuf[0] + sm.pool.sbuf[1] + sm.pool.sbuf[2] + sm.pool.sbuf[3];
    if (total == 0.f) {                    // all rows masked: uniform alpha
      p0 = p1 = p2 = float4{0,0,0,0};
      for (int s = 0; s < 32; ++s) {
        const float4* rp = fb + (wid * 32 + s) * (En / 4);
        fma4(p0, 1.f, rp[lane]); fma4(p1, 1.f, rp[64 + lane]); fma4(p2, 1.f, rp[128 + lane]);
      }
      ((float4*)sm.pool.pbuf[wid])[lane] = p0;
      ((float4*)sm.pool.pbuf[wid])[64 + lane] = p1;
      ((float4*)sm.pool.pbuf[wid])[128 + lane] = p2;
      __syncthreads();
      total = 128.f;
    }
    const float inv = 1.f / total;
    if (t < 192) {
      float4 s0 = ((const float4*)sm.pool.pbuf[0])[t];
      float4 s1 = ((const float4*)sm.pool.pbuf[1])[t];
      float4 s2 = ((const float4*)sm.pool.pbuf[2])[t];
      float4 s3 = ((const float4*)sm.pool.pbuf[3])[t];
      ushort4 u;
      u.x = f2bf((s0.x+s1.x+s2.x+s3.x) * inv);
      u.y = f2bf((s0.y+s1.y+s2.y+s3.y) * inv);
      u.z = f2bf((s0.z+s1.z+s2.z+s3.z) * inv);
      u.w = f2bf((s0.w+s1.w+s2.w+s3.w) * inv);
      ((ushort4*)pooled)[(size_t)b * 192 + t] = u;
    }
    return;
  }

  if (bid < Bn + 2016) {                   // ---------------- pack ----------
    const int pair = (bid - Bn) * 4 + wid;
    const int q = lane >> 4, j = lane & 15;
    const float* src; unsigned short* dst; int kt;
    if (pair < 2880) {                     // expert: 120 ntiles x 24 kt
      int nt = pair / 24; kt = pair % 24;
      int col = nt * 16 + j;
      src = ew + (size_t)(col / HIDn) * (En * HIDn) + (col % HIDn);
      dst = Bpe + (size_t)pair * 512;
    } else {                               // gate: 9 heads x 24 ntiles x 24 kt
      int g = pair - 2880;
      int h = g / 576, rem = g % 576;
      int nt = rem / 24; kt = rem % 24;
      int col = nt * 16 + j;
      src = g1 + (size_t)h * (En * HIDn) + col;
      dst = Bpg + ((size_t)(h * 24 + nt) * 24 + kt) * 512;
    }
    unsigned short outv[8] __attribute__((aligned(16)));
    #pragma unroll
    for (int e = 0; e < 8; ++e) {
      int k = kt * 32 + q * 8 + e;
      outv[e] = f2bf(src[(size_t)k * HIDn]);
    }
    *(uint4*)&dst[lane * 8] = *(const uint4*)outv;
    return;
  }

  // -------- sort: stable counting sort by category, 128-padded tiles -------
  #pragma unroll
  for (int jj = 0; jj < NHn; ++jj) sm.srt.hist[jj][t] = 0;
  __syncthreads();
  for (int i = 0; i < 16; ++i) { int c = category[t * 16 + i]; sm.srt.hist[c][t]++; }
  __syncthreads();
  if (t < NHn) {
    int run = 0;
    for (int x = 0; x < 256; ++x) { int v = sm.srt.hist[t][x]; sm.srt.hist[t][x] = run; run += v; }
    sm.srt.total[t] = run;
  }
  __syncthreads();
  if (t == 0) {
    int pb = 0, mt = 0;
    for (int jj = 0; jj < NHn; ++jj) {
      sm.srt.padbase[jj] = pb;
      int tot = sm.srt.total[jj];
      int nt = (tot + 127) >> 7;
      for (int k2 = 0; k2 < nt; ++k2) {
        meta[1 + mt + k2] = jj;
        int vv = tot - (k2 << 7); if (vv > 128) vv = 128;
        meta[64 + mt + k2] = vv;
        sm.srt.tilecat[mt + k2] = jj;
      }
      mt += nt; pb += nt << 7;
    }
    meta[0] = mt; sm.srt.padTiles = mt;
  }
  __syncthreads();
  const int padM = sm.srt.padTiles << 7;
  for (int mm = t; mm < padM; mm += 256) {
    int h = sm.srt.tilecat[mm >> 7];
    if (mm - sm.srt.padbase[h] >= sm.srt.total[h]) rowsamp[mm] = 0;
  }
  for (int i = 0; i < 16; ++i) {           // stable scatter
    int idx = t * 16 + i; int c = category[idx];
    int off = sm.srt.hist[c][t]++;
    rowsamp[sm.srt.padbase[c] + off] = idx;
  }
}

// ====== K2: gemme (blocks 0..479) | gemmg (480..602), both LDS-staged ======
__global__ __launch_bounds__(256) void gemm_kernel(
    const unsigned short* __restrict__ pooled, const unsigned short* __restrict__ Bpe,
    const unsigned short* __restrict__ Bpg, const float* __restrict__ eb,
    const float* __restrict__ gb1, const float* __restrict__ g2,
    const int* __restrict__ category, const float* __restrict__ hw,
    const int* __restrict__ rowsamp, const int* __restrict__ meta,
    float* __restrict__ partial, float* __restrict__ glogp) {
  __shared__ __align__(16) struct {
    unsigned short Alds[128 * 40];
    unsigned short Blds[8 * 512];
    union {
      struct { float hwlds[NHn * HIDn]; float plds[2][128]; } e;
      struct { int rs[128]; float w2lds[640]; } g;
    } u;
  } sm;
  const int t = threadIdx.x, lane = t & 63, wid = t >> 6;
  const int wm = wid >> 1, wn = wid & 1;
  const int bid = blockIdx.x;
  const int r = t >> 2, c0 = (t & 3) * 8;
  const int arow = wm * 64 + (lane & 15);
  const int aq = (lane >> 4) * 8;
  const int lrb = wm * 64 + ((lane >> 4) << 2);
  const int cb = wn * 64 + (lane & 15);
  f32x4 acc[4][4] = {};

  if (bid < 480) {                         // -------------- gemme ----------
    const int bx = bid % 15, by = bid / 15;
    const int m0 = by * 128, ntg0 = bx * 8;
    for (int idx = t; idx < NHn * HIDn; idx += 256) sm.u.e.hwlds[idx] = hw[idx];
    for (int kt = 0; kt < 24; ++kt) {
      __syncthreads();
      *(uint4*)&sm.Alds[r * 40 + c0] =
          *(const uint4*)&pooled[(size_t)(m0 + r) * En + kt * 32 + c0];
      *(uint4*)&sm.Alds[(r + 64) * 40 + c0] =
          *(const uint4*)&pooled[(size_t)(m0 + r + 64) * En + kt * 32 + c0];
      #pragma unroll
      for (int rnd = 0; rnd < 2; ++rnd) {
        int chunk = t + rnd * 256;
        int nt = chunk >> 6, l2 = chunk & 63;
        *(uint4*)&sm.Blds[nt * 512 + l2 * 8] =
            *(const uint4*)&Bpe[((size_t)(ntg0 + nt) * 24 + kt) * 512 + l2 * 8];
      }
      __syncthreads();
      short8 af[4], bfv[4];
      #pragma unroll
      for (int i = 0; i < 4; ++i) af[i] = *(const short8*)&sm.Alds[(arow + i * 16) * 40 + aq];
      #pragma unroll
      for (int i = 0; i < 4; ++i) bfv[i] = *(const short8*)&sm.Blds[(wn * 4 + i) * 512 + lane * 8];
      #pragma unroll
      for (int i = 0; i < 4; ++i)
        #pragma unroll
        for (int jj = 0; jj < 4; ++jj)
          acc[i][jj] = __builtin_amdgcn_mfma_f32_16x16x32_bf16(af[i], bfv[jj], acc[i][jj], 0, 0, 0);
    }
    const int kexp = bx / 3, lcolbase = (bx % 3) * 128;
    (void)kexp;
    float sums[4][4];
    #pragma unroll
    for (int i = 0; i < 4; ++i) {
      #pragma unroll
      for (int rr = 0; rr < 4; ++rr) {
        const int row = m0 + lrb + i * 16 + rr;
        const int cat = category[row];
        float s = 0.f;
        #pragma unroll
        for (int jj = 0; jj < 4; ++jj) {
          int cl = cb + jj * 16;
          float v = acc[i][jj][rr] + eb[bx * 128 + cl];
          v = fmaxf(v, 0.f);
          s = fmaf(v, sm.u.e.hwlds[cat * HIDn + lcolbase + cl], s);
        }
        #pragma unroll
        for (int off = 8; off; off >>= 1) s += __shfl_xor(s, off);
        sums[i][rr] = s;
      }
    }
    __syncthreads();
    if ((lane & 15) == 0) {
      #pragma unroll
      for (int i = 0; i < 4; ++i)
        #pragma unroll
        for (int rr = 0; rr < 4; ++rr)
          sm.u.e.plds[wn][lrb + i * 16 + rr] = sums[i][rr];
    }
    __syncthreads();
    if (t < 128) partial[(size_t)bx * Bn + m0 + t] = sm.u.e.plds[0][t] + sm.u.e.plds[1][t];
    return;
  }

  // ---------------- gemmg: sorted-gather gate GEMM + W2 epilogue ----------
  const int gid = bid - 480;
  const int mt = gid / 3, bxg = gid % 3;
  if (mt >= meta[0]) return;
  const int h = meta[1 + mt], valid = meta[64 + mt];
  if (t < 128) sm.u.g.rs[t] = rowsamp[mt * 128 + t];
  const float* w2src = g2 + ((size_t)h * HIDn + bxg * 128) * 5;
  for (int idx = t; idx < 640; idx += 256) sm.u.g.w2lds[idx] = w2src[idx];
  for (int kt = 0; kt < 24; ++kt) {
    __syncthreads();
    *(uint4*)&sm.Alds[r * 40 + c0] =
        *(const uint4*)&pooled[(size_t)sm.u.g.rs[r] * En + kt * 32 + c0];
    *(uint4*)&sm.Alds[(r + 64) * 40 + c0] =
        *(const uint4*)&pooled[(size_t)sm.u.g.rs[r + 64] * En + kt * 32 + c0];
    #pragma unroll
    for (int rnd = 0; rnd < 2; ++rnd) {
      int chunk = t + rnd * 256;
      int nt = chunk >> 6, l2 = chunk & 63;
      *(uint4*)&sm.Blds[nt * 512 + l2 * 8] =
          *(const uint4*)&Bpg[((size_t)(h * 24 + bxg * 8 + nt) * 24 + kt) * 512 + l2 * 8];
    }
    __syncthreads();
    short8 af[4], bfv[4];
    #pragma unroll
    for (int i = 0; i < 4; ++i) af[i] = *(const short8*)&sm.Alds[(arow + i * 16) * 40 + aq];
    #pragma unroll
    for (int i = 0; i < 4; ++i) bfv[i] = *(const short8*)&sm.Blds[(wn * 4 + i) * 512 + lane * 8];
    #pragma unroll
    for (int i = 0; i < 4; ++i)
      #pragma unroll
      for (int jj = 0; jj < 4; ++jj)
        acc[i][jj] = __builtin_amdgcn_mfma_f32_16x16x32_bf16(af[i], bfv[jj], acc[i][jj], 0, 0, 0);
  }
  #pragma unroll
  for (int i = 0; i < 4; ++i) {
    #pragma unroll
    for (int rr = 0; rr < 4; ++rr) {
      const int lrow = lrb + i * 16 + rr;
      float s[5] = {0.f, 0.f, 0.f, 0.f, 0.f};
      #pragma unroll
      for (int jj = 0; jj < 4; ++jj) {
        int cl = cb + jj * 16;
        float v = acc[i][jj][rr] + gb1[h * HIDn + bxg * 128 + cl];
        v = fmaxf(v, 0.f);
        #pragma unroll
        for (int k = 0; k < 5; ++k) s[k] = fmaf(v, sm.u.g.w2lds[cl * 5 + k], s[k]);
      }
      #pragma unroll
      for (int k = 0; k < 5; ++k)
        #pragma unroll
        for (int off = 8; off; off >>= 1) s[k] += __shfl_xor(s[k], off);
      if ((lane & 15) == 0 && lrow < valid) {
        int samp = sm.u.g.rs[lrow];
        #pragma unroll
        for (int k = 0; k < 5; ++k)
          glogp[((size_t)bxg * Bn + samp) * 5 + k] = s[k];
      }
    }
  }
}

// ====== K3: gate softmax + expert combine + head bias + sigmoid ============
__global__ __launch_bounds__(256) void final_kernel(
    const float* __restrict__ partial, const float* __restrict__ glogp,
    const float* __restrict__ gb2, const int* __restrict__ category,
    const float* __restrict__ hb, float* __restrict__ out) {
  const int row = blockIdx.x * 256 + threadIdx.x;
  const int cat = category[row];
  float gl[5];
  #pragma unroll
  for (int k = 0; k < 5; ++k)
    gl[k] = gb2[cat * 5 + k]
          + glogp[((size_t)0 * Bn + row) * 5 + k]
          + glogp[((size_t)1 * Bn + row) * 5 + k]
          + glogp[((size_t)2 * Bn + row) * 5 + k];
  float mx = fmaxf(fmaxf(fmaxf(gl[0], gl[1]), fmaxf(gl[2], gl[3])), gl[4]);
  float ek[5], es = 0.f;
  #pragma unroll
  for (int k = 0; k < 5; ++k) { ek[k] = __expf(gl[k] - mx); es += ek[k]; }
  const float einv = 1.f / es;
  float s = 0.f;
  #pragma unroll
  for (int k = 0; k < 5; ++k) {
    float ps = partial[(size_t)(3 * k) * Bn + row]
             + partial[(size_t)(3 * k + 1) * Bn + row]
             + partial[(size_t)(3 * k + 2) * Bn + row];
    s = fmaf(ek[k] * einv, ps, s);
  }
  s += hb[cat];
  out[row] = 1.f / (1.f + __expf(-s));
}

extern "C" void kernel_launch(void* const* d_in, const int* in_sizes, int n_in,
                              void* d_out, int out_size, void* d_ws, size_t ws_size,
                              hipStream_t stream) {
  const float* feature  = (const float*)d_in[0];
  const int*   masks    = (const int*)d_in[1];
  const int*   category = (const int*)d_in[2];
  const float* attn_w   = (const float*)d_in[3];
  // d_in[4] attn_b cancels in softmax
  const float* gate_w1  = (const float*)d_in[5];
  const float* gate_b1  = (const float*)d_in[6];
  const float* gate_w2  = (const float*)d_in[7];
  const float* gate_b2  = (const float*)d_in[8];
  const float* expert_w = (const float*)d_in[9];
  const float* expert_b = (const float*)d_in[10];
  const float* head_w   = (const float*)d_in[11];
  const float* head_b   = (const float*)d_in[12];
  float* out = (float*)d_out;

  char* ws = (char*)d_ws;
  unsigned short* pooled = (unsigned short*)(ws);             //  6,291,456 B
  unsigned short* Bpe    = (unsigned short*)(ws + 6291456);   //  2,949,120 B
  unsigned short* Bpg    = (unsigned short*)(ws + 9240576);   //  5,308,416 B
  int* rowsamp           = (int*)(ws + 14548992);             //     20,992 B
  int* meta              = (int*)(ws + 14569984);             //        512 B
  float* glogp           = (float*)(ws + 14570496);           //    245,760 B
  float* partial         = (float*)(ws + 14816256);           //    245,760 B

  prep_kernel<<<dim3(Bn + 2016 + 1), dim3(256), 0, stream>>>(
      feature, masks, attn_w, expert_w, gate_w1, category,
      pooled, Bpe, Bpg, rowsamp, meta);
  gemm_kernel<<<dim3(480 + 3 * MAXTILES), dim3(256), 0, stream>>>(
      pooled, Bpe, Bpg, expert_b, gate_b1, gate_w2, category, head_w,
      rowsamp, meta, partial, glogp);
  final_kernel<<<dim3(16), dim3(256), 0, stream>>>(
      partial, glogp, gate_b2, category, head_b, out);
}